// Round 8
// baseline (602.980 us; speedup 1.0000x reference)
//
#include <hip/hip_runtime.h>

// ILCBaseNode: T=32 steps of IF-neuron + grouped-conv feedback.
// One wave (64 lanes) per (batch, group) chain; lane o = output neuron o.
// 32768 chains = 8192 blocks x 4 waves.
//
// R8: R7's proven-correct asm matvec + amdgpu_waves_per_eu(4,4).
//     R7's issue-budget arithmetic closed the diagnosis: 278us x 2.4GHz x
//     84.5% busy / 1024 wave-steps/SIMD = 547 cyc/step = 273 instrs/step
//     = 129 (pinned asm) + 16 (loop overhead) + 128 (v_accvgpr_read x64 +
//     v_accvgpr_write x64). The allocator keeps w[] AGPR-homed and
//     satisfies the "+v" in-out operands with copies around each asm
//     block, because its DESIRED occupancy is the LLVM default (8
//     waves/EU => 64-reg arch target), not launch_bounds' min of 4 --
//     and the gfx90a-era cost model counts occupancy from arch VGPRs
//     only, so AGPR residency looks free. waves_per_eu(4,4) pins the
//     occupancy goal to exactly 4 waves/EU = 128-reg budget; demand is
//     ~110, so w[] arch-homes and the 128 copies/step vanish.
//     (NB: this attribute was R2's plan but R2 died on container infra
//     and was never measured.)
//     Prediction: VGPR ~104-112, occ ~50%, dispatch ~150-170us.
//     If VGPR stays 40 / dur flat: allocator unpersuadable -> pivot
//     structure in R9.
//     Ruled out (do not revisit): LDS spike broadcast (R1: 377us,
//     LDS-pipe-bound); any accumulation reorder incl. MFMA/split-acc
//     (fb reorder diff ~1e-7 x 6.7e7 threshold crossings -> ~5 expected
//     spike flips; one flip = absmax 1.0 > 0.02 threshold); ballot+SALU
//     bit-expand (single scalar unit/CU -> worse).

#define T_STEPS 32
#define BATCH 512
#define OUTD 4096           // 64 groups * 64 neurons
#define STEP_STRIDE ((size_t)BATCH * OUTD)

// One 16-wide matvec slice. Operands: %0-%4 = SGPR temps t0-t4, %5 = acc
// (early-clobber in-out), %6-%21 = W[0..15] (in-out "+v"), %22 = sfr
// (spike VGPR). 5-deep readlane prologue, then fmac/readlane interleave;
// every readlane SGPR write has >=4 instruction slots before its consuming
// fmac (v_readlane is lane-crossing / non-interlocked). Accumulation
// strictly ascending d, single accumulator (bit-exact; s[d] in {0,1}).
#define MV16(pre,d0,d1,d2,d3,d4,d5,d6,d7,d8,d9,d10,d11,d12,d13,d14,d15, W) \
  asm(pre                                                                 \
      "v_readlane_b32 %0, %22, " #d0 "\n\t"                               \
      "v_readlane_b32 %1, %22, " #d1 "\n\t"                               \
      "v_readlane_b32 %2, %22, " #d2 "\n\t"                               \
      "v_readlane_b32 %3, %22, " #d3 "\n\t"                               \
      "v_readlane_b32 %4, %22, " #d4 "\n\t"                               \
      "v_fmac_f32 %5, %0, %6\n\t"                                         \
      "v_readlane_b32 %0, %22, " #d5 "\n\t"                               \
      "v_fmac_f32 %5, %1, %7\n\t"                                         \
      "v_readlane_b32 %1, %22, " #d6 "\n\t"                               \
      "v_fmac_f32 %5, %2, %8\n\t"                                         \
      "v_readlane_b32 %2, %22, " #d7 "\n\t"                               \
      "v_fmac_f32 %5, %3, %9\n\t"                                         \
      "v_readlane_b32 %3, %22, " #d8 "\n\t"                               \
      "v_fmac_f32 %5, %4, %10\n\t"                                        \
      "v_readlane_b32 %4, %22, " #d9 "\n\t"                               \
      "v_fmac_f32 %5, %0, %11\n\t"                                        \
      "v_readlane_b32 %0, %22, " #d10 "\n\t"                              \
      "v_fmac_f32 %5, %1, %12\n\t"                                        \
      "v_readlane_b32 %1, %22, " #d11 "\n\t"                              \
      "v_fmac_f32 %5, %2, %13\n\t"                                        \
      "v_readlane_b32 %2, %22, " #d12 "\n\t"                              \
      "v_fmac_f32 %5, %3, %14\n\t"                                        \
      "v_readlane_b32 %3, %22, " #d13 "\n\t"                              \
      "v_fmac_f32 %5, %4, %15\n\t"                                        \
      "v_readlane_b32 %4, %22, " #d14 "\n\t"                              \
      "v_fmac_f32 %5, %0, %16\n\t"                                        \
      "v_readlane_b32 %0, %22, " #d15 "\n\t"                              \
      "v_fmac_f32 %5, %1, %17\n\t"                                        \
      "v_fmac_f32 %5, %2, %18\n\t"                                        \
      "v_fmac_f32 %5, %3, %19\n\t"                                        \
      "v_fmac_f32 %5, %4, %20\n\t"                                        \
      "v_fmac_f32 %5, %0, %21\n\t"                                        \
      : "=&s"(t0), "=&s"(t1), "=&s"(t2), "=&s"(t3), "=&s"(t4),            \
        "+&v"(acc),                                                       \
        "+v"(W[0]),  "+v"(W[1]),  "+v"(W[2]),  "+v"(W[3]),                \
        "+v"(W[4]),  "+v"(W[5]),  "+v"(W[6]),  "+v"(W[7]),                \
        "+v"(W[8]),  "+v"(W[9]),  "+v"(W[10]), "+v"(W[11]),               \
        "+v"(W[12]), "+v"(W[13]), "+v"(W[14]), "+v"(W[15])                \
      : "v"(sfr))

__global__ __launch_bounds__(256)
__attribute__((amdgpu_waves_per_eu(4, 4)))
void ilc_snn_kernel(const float* __restrict__ x_seq,
                    const float* __restrict__ conn_w,
                    const float* __restrict__ conn_b,
                    float* __restrict__ out)
{
    const int lane  = threadIdx.x & 63;
    const int wid   = threadIdx.x >> 6;
    const int chain = blockIdx.x * 4 + wid;   // 0..32767
    const int b     = chain >> 6;             // 0..511
    const int a     = chain & 63;             // 0..63

    // Lane o holds weight row w[a][o][0..63].
    float w[64];
    const float* wrow = conn_w + ((size_t)(a * 64 + lane)) * 64;
#pragma unroll
    for (int k = 0; k < 16; ++k) {
        const float4 q = *(const float4*)(wrow + 4 * k);
        w[4 * k + 0] = q.x;
        w[4 * k + 1] = q.y;
        w[4 * k + 2] = q.z;
        w[4 * k + 3] = q.w;
    }
    const float bias = conn_b[a * 64 + lane];

    const size_t base = (size_t)b * OUTD + (size_t)(a * 64 + lane);
    const float* xp = x_seq + base;
    float* op = out + base;

    float v = 0.0f, fb = 0.0f;
    float xt = xp[0];   // prefetch step 0
    int t0, t1, t2, t3, t4; // rotating SGPR temps for the asm matvec

    for (int t = 0; t < T_STEPS; ++t) {
        // Prefetch next step's input before the long fmac chain.
        float xnext = 0.0f;
        if (t + 1 < T_STEPS) xnext = xp[(size_t)(t + 1) * STEP_STRIDE];

        // Charge
        const float x = xt + fb;   // x_t + feedback (matches ref op order)
        v = v + x;
        // Fire (heaviside on v - 1.0)
        const bool  sp = (v - 1.0f) >= 0.0f;
        const float sf = sp ? 1.0f : 0.0f;
        // Hard reset
        v = sp ? 0.0f : v;
        // Emit spike
        op[(size_t)t * STEP_STRIDE] = sf;

        // Feedback matvec: fb[o] = sum_{d=0..63} s[d] * w[o][d] + bias[o]
        float acc = 0.0f;
        const float sfr = sf;
        // Block 1 carries s_nop 3: sfr was just written by a VALU
        // (v_cndmask); readlane's lane-crossing source read is not
        // interlocked against it.
        MV16("s_nop 3\n\t",
              0, 1, 2, 3, 4, 5, 6, 7, 8, 9,10,11,12,13,14,15, (&w[0]));
        MV16("",
             16,17,18,19,20,21,22,23,24,25,26,27,28,29,30,31, (&w[16]));
        MV16("",
             32,33,34,35,36,37,38,39,40,41,42,43,44,45,46,47, (&w[32]));
        MV16("",
             48,49,50,51,52,53,54,55,56,57,58,59,60,61,62,63, (&w[48]));
        fb = acc + bias;

        xt = xnext;
    }
}

extern "C" void kernel_launch(void* const* d_in, const int* in_sizes, int n_in,
                              void* d_out, int out_size, void* d_ws, size_t ws_size,
                              hipStream_t stream) {
    const float* x_seq  = (const float*)d_in[0];
    const float* conn_w = (const float*)d_in[1];
    const float* conn_b = (const float*)d_in[2];
    float* out = (float*)d_out;

    dim3 grid(8192);   // 32768 chains / 4 waves per block
    dim3 block(256);
    hipLaunchKernelGGL(ilc_snn_kernel, grid, block, 0, stream,
                       x_seq, conn_w, conn_b, out);
}